// Round 1
// baseline (98.114 us; speedup 1.0000x reference)
//
#include <hip/hip_runtime.h>

// GeneAttentionLayer fused single-pass kernel.
// ref: att[n,c,g] = (attention[c]·x[n,g]) * comp[c,g];
//      w = exp(leaky_relu(att)) * (att != 0);
//      out[n,c,:] = sum_g w * x[n,g,:] / sum_g w
// comp is a partition (comp[c,g] = [g % C == c]), so each gene feeds exactly
// one chromosome -> one streaming pass over x suffices.

constexpr int N_ = 256;
constexpr int C_ = 24;
constexpr int G_ = 2048;
constexpr int H_ = 256;
constexpr int CPB = 4;                    // chromosomes per block (1 per wave)
constexpr int BLOCKS_PER_N = C_ / CPB;    // 6

__global__ __launch_bounds__(256)
void gene_attn_fused(const float* __restrict__ x,          // [N,G,H]
                     const float* __restrict__ attention,  // [C,H]
                     const float* __restrict__ comp,       // [C,G]
                     float* __restrict__ out)              // [N,C,H]
{
    const int tid  = threadIdx.x;
    const int lane = tid & 63;
    const int wave = tid >> 6;
    const int bid  = blockIdx.x;
    const int n    = bid / BLOCKS_PER_N;
    const int c    = (bid % BLOCKS_PER_N) * CPB + wave;

    const float4* __restrict__ xr =
        reinterpret_cast<const float4*>(x + (size_t)n * G_ * H_);
    const float4 av =
        reinterpret_cast<const float4*>(attention)[c * (H_ / 4) + lane];
    const float* __restrict__ crow = comp + c * G_;

    float4 acc = make_float4(0.f, 0.f, 0.f, 0.f);
    float  denom = 0.f;

    // genes that can have comp[c,g] != 0: g = c, c+C, c+2C, ...
    #pragma unroll 4
    for (int g = c; g < G_; g += C_) {
        const float  compv = crow[g];
        const float4 xv    = xr[g * (H_ / 4) + lane];
        float p = xv.x * av.x + xv.y * av.y + xv.z * av.z + xv.w * av.w;
        #pragma unroll
        for (int off = 32; off > 0; off >>= 1)
            p += __shfl_xor(p, off, 64);
        const float att = p * compv;
        float wgt = 0.f;
        if (att != 0.f) {
            const float l = (att > 0.f) ? att : 0.01f * att;
            wgt = expf(l);
        }
        acc.x += wgt * xv.x;
        acc.y += wgt * xv.y;
        acc.z += wgt * xv.z;
        acc.w += wgt * xv.w;
        denom += wgt;
    }

    const float inv = 1.0f / denom;
    float4 o = make_float4(acc.x * inv, acc.y * inv, acc.z * inv, acc.w * inv);
    reinterpret_cast<float4*>(out)[((size_t)n * C_ + c) * (H_ / 4) + lane] = o;
}

extern "C" void kernel_launch(void* const* d_in, const int* in_sizes, int n_in,
                              void* d_out, int out_size, void* d_ws, size_t ws_size,
                              hipStream_t stream) {
    const float* x         = (const float*)d_in[0];
    const float* attention = (const float*)d_in[1];
    const float* comp      = (const float*)d_in[2];
    float*       out       = (float*)d_out;

    dim3 grid(N_ * BLOCKS_PER_N);
    dim3 block(256);
    gene_attn_fused<<<grid, block, 0, stream>>>(x, attention, comp, out);
}

// Round 2
// 86.635 us; speedup vs baseline: 1.1325x; 1.1325x over previous
//
#include <hip/hip_runtime.h>

// GeneAttentionLayer fused single-pass kernel (R1 tuning).
// att[n,c,g] = (attention[c]·x[n,g]) * comp[c,g]; w = exp(leaky_relu(att))*(att!=0);
// out[n,c,:] = sum_g w*x[n,g,:] / sum_g w.
// comp is a partition (comp[c,g] = [g%C==c]) -> one streaming pass over x.
// R1: CPB=8 (8 adjacent gene rows in flight per block), unroll 8, nontemporal
// loads (x has zero reuse), __expf. Memory-bound target: 518MB @ ~6.3TB/s ≈ 82us.

constexpr int N_ = 256;
constexpr int C_ = 24;
constexpr int G_ = 2048;
constexpr int H_ = 256;
constexpr int CPB = 8;                    // chromosomes per block (1 per wave)
constexpr int BLOCKS_PER_N = C_ / CPB;    // 3

using f32x4 = __attribute__((ext_vector_type(4))) float;

__global__ __launch_bounds__(512)
void gene_attn_fused(const float* __restrict__ x,          // [N,G,H]
                     const float* __restrict__ attention,  // [C,H]
                     const float* __restrict__ comp,       // [C,G]
                     float* __restrict__ out)              // [N,C,H]
{
    const int tid  = threadIdx.x;
    const int lane = tid & 63;
    const int wave = tid >> 6;
    const int bid  = blockIdx.x;
    const int n    = bid / BLOCKS_PER_N;
    const int c    = (bid % BLOCKS_PER_N) * CPB + wave;

    const f32x4* __restrict__ xr =
        reinterpret_cast<const f32x4*>(x + (size_t)n * G_ * H_);
    const f32x4 av =
        reinterpret_cast<const f32x4*>(attention)[c * (H_ / 4) + lane];
    const float* __restrict__ crow = comp + c * G_;

    f32x4 acc = {0.f, 0.f, 0.f, 0.f};
    float denom = 0.f;

    // genes with comp[c,g] possibly nonzero: g = c, c+C, c+2C, ...
    #pragma unroll 8
    for (int g = c; g < G_; g += C_) {
        const float compv = crow[g];
        const f32x4 xv = __builtin_nontemporal_load(&xr[g * (H_ / 4) + lane]);
        float p = xv.x * av.x + xv.y * av.y + xv.z * av.z + xv.w * av.w;
        #pragma unroll
        for (int off = 32; off > 0; off >>= 1)
            p += __shfl_xor(p, off, 64);
        const float att = p * compv;
        float wgt = 0.f;
        if (att != 0.f)
            wgt = __expf(att > 0.f ? att : 0.01f * att);
        acc += xv * wgt;
        denom += wgt;
    }

    const float inv = 1.0f / denom;
    const f32x4 o = acc * inv;
    reinterpret_cast<f32x4*>(out)[((size_t)n * C_ + c) * (H_ / 4) + lane] = o;
}

extern "C" void kernel_launch(void* const* d_in, const int* in_sizes, int n_in,
                              void* d_out, int out_size, void* d_ws, size_t ws_size,
                              hipStream_t stream) {
    const float* x         = (const float*)d_in[0];
    const float* attention = (const float*)d_in[1];
    const float* comp      = (const float*)d_in[2];
    float*       out       = (float*)d_out;

    dim3 grid(N_ * BLOCKS_PER_N);
    dim3 block(CPB * 64);
    gene_attn_fused<<<grid, block, 0, stream>>>(x, attention, comp, out);
}

// Round 3
// 86.004 us; speedup vs baseline: 1.1408x; 1.0073x over previous
//
#include <hip/hip_runtime.h>

// GeneAttentionLayer fused single-pass kernel (R2 tuning).
// att[n,c,g] = (attention[c]·x[n,g]) * comp[c,g]; w = exp(leaky_relu(att))*(att!=0);
// out[n,c,:] = sum_g w*x[n,g,:] / sum_g w.
// comp is a partition (comp[c,g] = [g%C==c]) -> one streaming pass over x.
// R2: CPB=12 (12 KB contiguous per block-iteration, the max given c==g mod 24
// and the 1024-thread limit), nontemporal load+store, __expf.
// Memory-bound target: 518 MB @ ~6.3 TB/s ≈ 82 us.

constexpr int N_ = 256;
constexpr int C_ = 24;
constexpr int G_ = 2048;
constexpr int H_ = 256;
constexpr int CPB = 12;                   // chromosomes per block (1 per wave)
constexpr int BLOCKS_PER_N = C_ / CPB;    // 2

using f32x4 = __attribute__((ext_vector_type(4))) float;

__global__ __launch_bounds__(CPB * 64)
void gene_attn_fused(const float* __restrict__ x,          // [N,G,H]
                     const float* __restrict__ attention,  // [C,H]
                     const float* __restrict__ comp,       // [C,G]
                     float* __restrict__ out)              // [N,C,H]
{
    const int tid  = threadIdx.x;
    const int lane = tid & 63;
    const int wave = tid >> 6;
    const int bid  = blockIdx.x;
    const int n    = bid / BLOCKS_PER_N;
    const int c    = (bid % BLOCKS_PER_N) * CPB + wave;

    const f32x4* __restrict__ xr =
        reinterpret_cast<const f32x4*>(x + (size_t)n * G_ * H_);
    const f32x4 av =
        reinterpret_cast<const f32x4*>(attention)[c * (H_ / 4) + lane];
    const float* __restrict__ crow = comp + c * G_;

    f32x4 acc = {0.f, 0.f, 0.f, 0.f};
    float denom = 0.f;

    // genes with comp[c,g] possibly nonzero: g = c, c+C, c+2C, ...
    #pragma unroll 8
    for (int g = c; g < G_; g += C_) {
        const float compv = crow[g];
        const f32x4 xv = __builtin_nontemporal_load(&xr[g * (H_ / 4) + lane]);
        float p = xv.x * av.x + xv.y * av.y + xv.z * av.z + xv.w * av.w;
        #pragma unroll
        for (int off = 32; off > 0; off >>= 1)
            p += __shfl_xor(p, off, 64);
        const float att = p * compv;
        float wgt = 0.f;
        if (att != 0.f)
            wgt = __expf(att > 0.f ? att : 0.01f * att);
        acc += xv * wgt;
        denom += wgt;
    }

    const float inv = 1.0f / denom;
    const f32x4 o = acc * inv;
    __builtin_nontemporal_store(
        o, &reinterpret_cast<f32x4*>(out)[((size_t)n * C_ + c) * (H_ / 4) + lane]);
}

extern "C" void kernel_launch(void* const* d_in, const int* in_sizes, int n_in,
                              void* d_out, int out_size, void* d_ws, size_t ws_size,
                              hipStream_t stream) {
    const float* x         = (const float*)d_in[0];
    const float* attention = (const float*)d_in[1];
    const float* comp      = (const float*)d_in[2];
    float*       out       = (float*)d_out;

    dim3 grid(N_ * BLOCKS_PER_N);
    dim3 block(CPB * 64);
    gene_attn_fused<<<grid, block, 0, stream>>>(x, attention, comp, out);
}